// Round 6
// baseline (1899.396 us; speedup 1.0000x reference)
//
#include <hip/hip_runtime.h>
#include <math.h>

#define BATCH 65536
#define FDIM 16
#define CDIM 128
#define HDIM 256
#define NL 8
#define KBINS 8
#define TDIM 8
#define PD 23
#define TBV 3.0f
#define K1 160      // GEMM1 K: 128 ctx + 8 xi + 24 zero
#define N3 184      // real N of GEMM3
#define N3P 192     // padded N of GEMM3
#define PSTR 197    // p LDS row stride (f32 words)
#define MROWS 128   // rows per WG

typedef _Float16 f16;
typedef __attribute__((ext_vector_type(8))) _Float16 f16x8;
typedef __attribute__((ext_vector_type(4))) float f32x4;

__device__ __forceinline__ void splitf(float v, f16* h, f16* l) {
    f16 hv = (f16)v;
    *h = hv;
    *l = (f16)(v - (float)hv);
}

// ---------------- weight conversion (transposed to [N][K], split hi/lo) ----
__global__ __launch_bounds__(256)
void conv_w1_kernel(const float* __restrict__ W1,
                    f16* __restrict__ Wh, f16* __restrict__ Wl) {
    int idx = blockIdx.x * 256 + threadIdx.x;
    if (idx >= NL * HDIM * K1) return;
    int l = idx / (HDIM * K1);
    int rem = idx - l * HDIM * K1;
    int n = rem / K1;
    int k = rem - n * K1;
    int row = (k < 128) ? (8 + k) : ((k < 136) ? (k - 128) : -1);
    float v = (row >= 0) ? W1[((size_t)l * 136 + row) * HDIM + n] : 0.f;
    f16 hv, lv; splitf(v, &hv, &lv);
    Wh[idx] = hv; Wl[idx] = lv;
}

__global__ __launch_bounds__(256)
void conv_w2_kernel(const float* __restrict__ W2,
                    f16* __restrict__ Wh, f16* __restrict__ Wl) {
    int idx = blockIdx.x * 256 + threadIdx.x;
    if (idx >= NL * HDIM * HDIM) return;
    int l = idx / (HDIM * HDIM);
    int rem = idx - l * HDIM * HDIM;
    int n = rem >> 8;
    int k = rem & 255;
    f16 hv, lv; splitf(W2[((size_t)l * HDIM + k) * HDIM + n], &hv, &lv);
    Wh[idx] = hv; Wl[idx] = lv;
}

__global__ __launch_bounds__(256)
void conv_w3_kernel(const float* __restrict__ W3,
                    f16* __restrict__ Wh, f16* __restrict__ Wl) {
    int idx = blockIdx.x * 256 + threadIdx.x;
    if (idx >= NL * N3P * HDIM) return;
    int l = idx / (N3P * HDIM);
    int rem = idx - l * N3P * HDIM;
    int n = rem >> 8;
    int k = rem & 255;
    float v = (n < N3) ? W3[((size_t)l * HDIM + k) * N3 + n] : 0.f;
    f16 hv, lv; splitf(v, &hv, &lv);
    Wh[idx] = hv; Wl[idx] = lv;
}

__global__ __launch_bounds__(256)
void conv_ctx_kernel(const float* __restrict__ ctx,
                     f16* __restrict__ ch, f16* __restrict__ cl) {
    size_t idx = ((size_t)blockIdx.x * 256 + threadIdx.x) * 4;
    if (idx >= (size_t)BATCH * CDIM) return;
    float4 v = *(const float4*)&ctx[idx];
    f16 h, l;
    splitf(v.x, &h, &l); ch[idx + 0] = h; cl[idx + 0] = l;
    splitf(v.y, &h, &l); ch[idx + 1] = h; cl[idx + 1] = l;
    splitf(v.z, &h, &l); ch[idx + 2] = h; cl[idx + 2] = l;
    splitf(v.w, &h, &l); ch[idx + 3] = h; cl[idx + 3] = l;
}

__device__ __forceinline__ float softplusf(float v) {
    return fmaxf(v, 0.f) + log1pf(expf(-fabsf(v)));
}

// ---------------- fused flow kernel ----------------
// 128 rows per WG, 512 threads (8 waves, 2 per SIMD, 1 WG/CU).
// sH: two 64KB f16 planes (hi/lo), XOR-swizzled [row][k] (row<128, k<256).
// Overlaid by sP (fp32 p buffer) between barriers.
__global__ __launch_bounds__(512, 2)
void flow_kernel(const float* __restrict__ in,
                 const f16* __restrict__ ctxh, const f16* __restrict__ ctxl,
                 const f16* __restrict__ W1h, const f16* __restrict__ W1l,
                 const f16* __restrict__ W2h, const f16* __restrict__ W2l,
                 const f16* __restrict__ W3h, const f16* __restrict__ W3l,
                 const float* __restrict__ b1, const float* __restrict__ b2,
                 const float* __restrict__ b3, const int* __restrict__ perms,
                 float* __restrict__ out) {
    __shared__ f16 sH[2 * MROWS * 256];          // 128KB
    __shared__ float sX[2][MROWS][17];           // 17.4KB
    __shared__ float sY[MROWS][8];               // 4KB
    __shared__ float sLd[MROWS][8];              // 4KB
    __shared__ float sLdet[MROWS];
    __shared__ int   sPerm[(NL - 1) * FDIM];

    const int tid = threadIdx.x;
    const int lane = tid & 63;
    const int w = tid >> 6;                      // 0..7
    const int wr = w >> 2, wc = w & 3;           // 2 row-halves x 4 col-groups
    const int lr = lane & 15, lh = lane >> 4;
    const int rbase = blockIdx.x * MROWS;
    float* sP = (float*)sH;                      // 128 x PSTR fp32 overlay

    // swizzled LDS helpers: byte = (row*512 + k*2) ^ ((row&7)<<4); plane=64KB
    auto lds_rd8 = [&](int plane, int row, int k) -> f16x8 {
        int byte = ((row << 9) + (k << 1)) ^ ((row & 7) << 4);
        return *(const f16x8*)((const char*)sH + (plane << 16) + byte);
    };
    auto lds_wr8 = [&](int plane, int row, int k, f16x8 v) {
        int byte = ((row << 9) + (k << 1)) ^ ((row & 7) << 4);
        *(f16x8*)((char*)sH + (plane << 16) + byte) = v;
    };
    auto lds_wr1 = [&](int plane, int row, int k, f16 v) {
        int byte = ((row << 9) + (k << 1)) ^ ((row & 7) << 4);
        *(f16*)((char*)sH + (plane << 16) + byte) = v;
    };

    // ---- init: x block, ldet, perms ----
    {
        int r = tid >> 2, c4 = (tid & 3) * 4;
        float4 v = *(const float4*)&in[(size_t)(rbase + r) * FDIM + c4];
        sX[0][r][c4 + 0] = fminf(fmaxf(v.x, -1.f), 1.f);
        sX[0][r][c4 + 1] = fminf(fmaxf(v.y, -1.f), 1.f);
        sX[0][r][c4 + 2] = fminf(fmaxf(v.z, -1.f), 1.f);
        sX[0][r][c4 + 3] = fminf(fmaxf(v.w, -1.f), 1.f);
    }
    if (tid < MROWS) sLdet[tid] = 0.f;
    if (tid < (NL - 1) * FDIM) sPerm[tid] = perms[tid];

    const int srow = tid >> 2, sc0 = (tid & 3) * 4;   // ctx staging
    const f16* gph = ctxh + (((size_t)(rbase + srow)) << 7) + sc0 * 8;
    const f16* gpl = ctxl + (((size_t)(rbase + srow)) << 7) + sc0 * 8;

    int cur = 0;
    for (int l = 0; l < NL; ++l) {
        // ---- (A) issue ctx plane loads (global, L2/L3-hot) before the barrier
        f16x8 cbh[4], cbl[4];
        #pragma unroll
        for (int s = 0; s < 4; ++s) {
            cbh[s] = ((const f16x8*)gph)[s];
            cbl[s] = ((const f16x8*)gpl)[s];
        }
        __syncthreads();
        // ---- (B) stage A1: ctx (k 0..127) ----
        #pragma unroll
        for (int s = 0; s < 4; ++s) {
            lds_wr8(0, srow, (sc0 + s) * 8, cbh[s]);
            lds_wr8(1, srow, (sc0 + s) * 8, cbl[s]);
        }
        // ---- xi (k 128..135) + zeros (136..159) ----
        if (tid < MROWS) {
            int r = tid, off = 1 - (l & 1);
            f16x8 h8, l8, z;
            #pragma unroll
            for (int k = 0; k < 8; ++k) {
                float v = sX[cur][r][2 * k + off];
                f16 hv, lv; splitf(v, &hv, &lv);
                h8[k] = hv; l8[k] = lv; z[k] = (f16)0.f;
            }
            lds_wr8(0, r, 128, h8); lds_wr8(1, r, 128, l8);
            lds_wr8(0, r, 136, z);  lds_wr8(1, r, 136, z);
            lds_wr8(0, r, 144, z);  lds_wr8(1, r, 144, z);
            lds_wr8(0, r, 152, z);  lds_wr8(1, r, 152, z);
        }
        __syncthreads();

        f32x4 acc[4][4];
        // ================= GEMM1: 256 cols, K=160 =================
        #pragma unroll
        for (int i = 0; i < 4; ++i)
            #pragma unroll
            for (int j = 0; j < 4; ++j) acc[i][j] = (f32x4){0.f, 0.f, 0.f, 0.f};
        for (int kt = 0; kt < 5; ++kt) {
            int k0 = kt * 32 + lh * 8;
            f16x8 ah[4], al[4];
            #pragma unroll
            for (int i = 0; i < 4; ++i) {
                ah[i] = lds_rd8(0, wr * 64 + i * 16 + lr, k0);
                al[i] = lds_rd8(1, wr * 64 + i * 16 + lr, k0);
            }
            #pragma unroll
            for (int j = 0; j < 4; ++j) {
                size_t o = (size_t)(l * HDIM + wc * 64 + j * 16 + lr) * K1 + k0;
                f16x8 bh = *(const f16x8*)(W1h + o);
                f16x8 bl = *(const f16x8*)(W1l + o);
                __builtin_amdgcn_s_setprio(1);
                #pragma unroll
                for (int i = 0; i < 4; ++i) {
                    acc[i][j] = __builtin_amdgcn_mfma_f32_16x16x32_f16(ah[i], bh, acc[i][j], 0, 0, 0);
                    acc[i][j] = __builtin_amdgcn_mfma_f32_16x16x32_f16(ah[i], bl, acc[i][j], 0, 0, 0);
                    acc[i][j] = __builtin_amdgcn_mfma_f32_16x16x32_f16(al[i], bh, acc[i][j], 0, 0, 0);
                }
                __builtin_amdgcn_s_setprio(0);
            }
        }
        __syncthreads();
        // h1 = relu(acc + b1) -> split into sH
        #pragma unroll
        for (int j = 0; j < 4; ++j) {
            int col = wc * 64 + j * 16 + lr;
            float bv = b1[l * HDIM + col];
            #pragma unroll
            for (int i = 0; i < 4; ++i)
                #pragma unroll
                for (int q = 0; q < 4; ++q) {
                    float v = fmaxf(acc[i][j][q] + bv, 0.f);
                    f16 hv, lv; splitf(v, &hv, &lv);
                    int row = wr * 64 + i * 16 + lh * 4 + q;
                    lds_wr1(0, row, col, hv);
                    lds_wr1(1, row, col, lv);
                }
        }
        __syncthreads();

        // ================= GEMM2: 256 cols, K=256 =================
        #pragma unroll
        for (int i = 0; i < 4; ++i)
            #pragma unroll
            for (int j = 0; j < 4; ++j) acc[i][j] = (f32x4){0.f, 0.f, 0.f, 0.f};
        for (int kt = 0; kt < 8; ++kt) {
            int k0 = kt * 32 + lh * 8;
            f16x8 ah[4], al[4];
            #pragma unroll
            for (int i = 0; i < 4; ++i) {
                ah[i] = lds_rd8(0, wr * 64 + i * 16 + lr, k0);
                al[i] = lds_rd8(1, wr * 64 + i * 16 + lr, k0);
            }
            #pragma unroll
            for (int j = 0; j < 4; ++j) {
                size_t o = (size_t)(l * HDIM + wc * 64 + j * 16 + lr) * HDIM + k0;
                f16x8 bh = *(const f16x8*)(W2h + o);
                f16x8 bl = *(const f16x8*)(W2l + o);
                __builtin_amdgcn_s_setprio(1);
                #pragma unroll
                for (int i = 0; i < 4; ++i) {
                    acc[i][j] = __builtin_amdgcn_mfma_f32_16x16x32_f16(ah[i], bh, acc[i][j], 0, 0, 0);
                    acc[i][j] = __builtin_amdgcn_mfma_f32_16x16x32_f16(ah[i], bl, acc[i][j], 0, 0, 0);
                    acc[i][j] = __builtin_amdgcn_mfma_f32_16x16x32_f16(al[i], bh, acc[i][j], 0, 0, 0);
                }
                __builtin_amdgcn_s_setprio(0);
            }
        }
        __syncthreads();
        // h2 = relu(acc + b2) -> split into sH
        #pragma unroll
        for (int j = 0; j < 4; ++j) {
            int col = wc * 64 + j * 16 + lr;
            float bv = b2[l * HDIM + col];
            #pragma unroll
            for (int i = 0; i < 4; ++i)
                #pragma unroll
                for (int q = 0; q < 4; ++q) {
                    float v = fmaxf(acc[i][j][q] + bv, 0.f);
                    f16 hv, lv; splitf(v, &hv, &lv);
                    int row = wr * 64 + i * 16 + lh * 4 + q;
                    lds_wr1(0, row, col, hv);
                    lds_wr1(1, row, col, lv);
                }
        }
        __syncthreads();

        // ================= GEMM3: 192 cols (48/wave), K=256 =================
        f32x4 acc3[4][3];
        #pragma unroll
        for (int i = 0; i < 4; ++i)
            #pragma unroll
            for (int j = 0; j < 3; ++j) acc3[i][j] = (f32x4){0.f, 0.f, 0.f, 0.f};
        for (int kt = 0; kt < 8; ++kt) {
            int k0 = kt * 32 + lh * 8;
            f16x8 ah[4], al[4];
            #pragma unroll
            for (int i = 0; i < 4; ++i) {
                ah[i] = lds_rd8(0, wr * 64 + i * 16 + lr, k0);
                al[i] = lds_rd8(1, wr * 64 + i * 16 + lr, k0);
            }
            #pragma unroll
            for (int j = 0; j < 3; ++j) {
                size_t o = (size_t)(l * N3P + wc * 48 + j * 16 + lr) * HDIM + k0;
                f16x8 bh = *(const f16x8*)(W3h + o);
                f16x8 bl = *(const f16x8*)(W3l + o);
                __builtin_amdgcn_s_setprio(1);
                #pragma unroll
                for (int i = 0; i < 4; ++i) {
                    acc3[i][j] = __builtin_amdgcn_mfma_f32_16x16x32_f16(ah[i], bh, acc3[i][j], 0, 0, 0);
                    acc3[i][j] = __builtin_amdgcn_mfma_f32_16x16x32_f16(ah[i], bl, acc3[i][j], 0, 0, 0);
                    acc3[i][j] = __builtin_amdgcn_mfma_f32_16x16x32_f16(al[i], bh, acc3[i][j], 0, 0, 0);
                }
                __builtin_amdgcn_s_setprio(0);
            }
        }
        __syncthreads();
        // p = acc3 + b3 -> sP (fp32, stride PSTR)
        #pragma unroll
        for (int j = 0; j < 3; ++j) {
            int col = wc * 48 + j * 16 + lr;
            float bv = (col < N3) ? b3[l * N3 + col] : 0.f;
            #pragma unroll
            for (int i = 0; i < 4; ++i)
                #pragma unroll
                for (int q = 0; q < 4; ++q) {
                    int row = wr * 64 + i * 16 + lh * 4 + q;
                    sP[row * PSTR + col] = acc3[i][j][q] + bv;
                }
        }
        __syncthreads();

        // ================= spline: wave w owns t=w; lane handles 2 rows ======
        {
            #pragma unroll
            for (int half = 0; half < 2; ++half) {
                int r = lane + half * 64;
                float xin = sX[cur][r][2 * w + (l & 1)];
                const float* pp = &sP[r * PSTR + w * PD];
                float uw[KBINS], uh[KBINS], ud[KBINS - 1];
                #pragma unroll
                for (int k = 0; k < KBINS; ++k) uw[k] = pp[k];
                #pragma unroll
                for (int k = 0; k < KBINS; ++k) uh[k] = pp[KBINS + k];
                #pragma unroll
                for (int k = 0; k < KBINS - 1; ++k) ud[k] = pp[2 * KBINS + k];

                float mw = uw[0];
                #pragma unroll
                for (int k = 1; k < KBINS; ++k) mw = fmaxf(mw, uw[k]);
                float ew[KBINS], swv = 0.f;
                #pragma unroll
                for (int k = 0; k < KBINS; ++k) { ew[k] = expf(uw[k] - mw); swv += ew[k]; }
                float cw[KBINS + 1];
                cw[0] = -TBV;
                {
                    float s = 0.f, inv = 1.f / swv;
                    #pragma unroll
                    for (int k = 0; k < KBINS; ++k) {
                        float wk = 0.001f + (1.f - 0.001f * KBINS) * ew[k] * inv;
                        s += wk;
                        cw[k + 1] = 2.f * TBV * s - TBV;
                    }
                    cw[KBINS] = TBV;
                }
                float mh = uh[0];
                #pragma unroll
                for (int k = 1; k < KBINS; ++k) mh = fmaxf(mh, uh[k]);
                float eh[KBINS], shv = 0.f;
                #pragma unroll
                for (int k = 0; k < KBINS; ++k) { eh[k] = expf(uh[k] - mh); shv += eh[k]; }
                float ch[KBINS + 1];
                ch[0] = -TBV;
                {
                    float s = 0.f, inv = 1.f / shv;
                    #pragma unroll
                    for (int k = 0; k < KBINS; ++k) {
                        float hk = 0.001f + (1.f - 0.001f * KBINS) * eh[k] * inv;
                        s += hk;
                        ch[k + 1] = 2.f * TBV * s - TBV;
                    }
                    ch[KBINS] = TBV;
                }
                float d[KBINS + 1];
                d[0] = 1.f; d[KBINS] = 1.f;
                #pragma unroll
                for (int k = 1; k < KBINS; ++k) d[k] = 0.001f + softplusf(ud[k - 1]);

                bool inside = (xin >= -TBV) && (xin <= TBV);
                float xs = fminf(fmaxf(xin, -TBV), TBV);
                int idx = 0;
                #pragma unroll
                for (int k = 1; k < KBINS; ++k) idx += (xs >= cw[k]) ? 1 : 0;
                float x0 = cw[0], x1 = cw[1], y0 = ch[0], y1 = ch[1], d0 = d[0], d1 = d[1];
                #pragma unroll
                for (int k = 0; k < KBINS; ++k) {
                    if (idx == k) { x0 = cw[k]; x1 = cw[k + 1]; y0 = ch[k]; y1 = ch[k + 1]; d0 = d[k]; d1 = d[k + 1]; }
                }
                float bw = x1 - x0, bh2 = y1 - y0;
                float delta = bh2 / bw;
                float th = (xs - x0) / bw;
                float th1m = th * (1.f - th);
                float num = bh2 * (delta * th * th + d0 * th1m);
                float den = delta + (d0 + d1 - 2.f * delta) * th1m;
                float y = y0 + num / den;
                float omth = 1.f - th;
                float dnum = delta * delta * (d1 * th * th + 2.f * delta * th1m + d0 * omth * omth);
                float ldv = logf(dnum) - 2.f * logf(den);
                sY[r][w] = inside ? y : xin;
                sLd[r][w] = inside ? ldv : 0.f;
            }
        }
        __syncthreads();

        // ================= rebuild x (+perm) and ldet =================
        {
            int r = tid >> 2, f0 = (tid & 3) * 4;
            if (l < NL - 1) {
                #pragma unroll
                for (int ff = 0; ff < 4; ++ff) {
                    int f = f0 + ff;
                    int g = sPerm[l * FDIM + f];
                    float v = ((g & 1) == (l & 1)) ? sY[r][g >> 1] : sX[cur][r][g];
                    sX[cur ^ 1][r][f] = v;
                }
                if (f0 == 0) {
                    float s = 0.f;
                    #pragma unroll
                    for (int t = 0; t < 8; ++t) s += sLd[r][t];
                    sLdet[r] += s;
                }
            } else {
                float ov[4];
                #pragma unroll
                for (int ff = 0; ff < 4; ++ff) {
                    int f = f0 + ff;
                    float v = ((f & 1) == (l & 1)) ? sY[r][f >> 1] : sX[cur][r][f];
                    ov[ff] = fminf(fmaxf(v, -1.f), 1.f);
                }
                float4 o = {ov[0], ov[1], ov[2], ov[3]};
                *(float4*)&out[(size_t)(rbase + r) * FDIM + f0] = o;
                if (f0 == 0) {
                    float s = 0.f;
                    #pragma unroll
                    for (int t = 0; t < 8; ++t) s += sLd[r][t];
                    out[(size_t)BATCH * FDIM + rbase + r] = sLdet[r] + s;
                }
            }
        }
        cur ^= 1;
    }
}

extern "C" void kernel_launch(void* const* d_in, const int* in_sizes, int n_in,
                              void* d_out, int out_size, void* d_ws, size_t ws_size,
                              hipStream_t stream) {
    (void)in_sizes; (void)n_in; (void)out_size; (void)ws_size;
    const float* inputs  = (const float*)d_in[0];
    const float* context = (const float*)d_in[1];
    const float* W1 = (const float*)d_in[2];
    const float* b1 = (const float*)d_in[3];
    const float* W2 = (const float*)d_in[4];
    const float* b2 = (const float*)d_in[5];
    const float* W3 = (const float*)d_in[6];
    const float* b3 = (const float*)d_in[7];
    const int*   perms = (const int*)d_in[8];
    float* out = (float*)d_out;

    f16* W1h = (f16*)d_ws;
    f16* W1l = W1h + (size_t)NL * HDIM * K1;
    f16* W2h = W1l + (size_t)NL * HDIM * K1;
    f16* W2l = W2h + (size_t)NL * HDIM * HDIM;
    f16* W3h = W2l + (size_t)NL * HDIM * HDIM;
    f16* W3l = W3h + (size_t)NL * N3P * HDIM;
    f16* ctxh = W3l + (size_t)NL * N3P * HDIM;
    f16* ctxl = ctxh + (size_t)BATCH * CDIM;

    int n1 = NL * HDIM * K1;
    conv_w1_kernel<<<(n1 + 255) / 256, 256, 0, stream>>>(W1, W1h, W1l);
    int n2 = NL * HDIM * HDIM;
    conv_w2_kernel<<<(n2 + 255) / 256, 256, 0, stream>>>(W2, W2h, W2l);
    int n3 = NL * N3P * HDIM;
    conv_w3_kernel<<<(n3 + 255) / 256, 256, 0, stream>>>(W3, W3h, W3l);
    int nc = BATCH * CDIM / 4;
    conv_ctx_kernel<<<(nc + 255) / 256, 256, 0, stream>>>(context, ctxh, ctxl);

    flow_kernel<<<BATCH / MROWS, 512, 0, stream>>>(
        inputs, ctxh, ctxl, W1h, W1l, W2h, W2l, W3h, W3l,
        b1, b2, b3, perms, out);
}

// Round 7
// 1102.622 us; speedup vs baseline: 1.7226x; 1.7226x over previous
//
#include <hip/hip_runtime.h>
#include <math.h>

#define BATCH 65536
#define FDIM 16
#define CDIM 128
#define HDIM 256
#define NL 8
#define KBINS 8
#define TDIM 8
#define PD 23
#define TBV 3.0f
#define K1 160      // GEMM1 K: 128 ctx + 8 xi + 24 zero
#define N3 184      // real N of GEMM3
#define N3P 192     // padded N of GEMM3
#define PSTR 197    // p LDS row stride (f32 words)

typedef _Float16 f16;
typedef __attribute__((ext_vector_type(8))) _Float16 f16x8;
typedef __attribute__((ext_vector_type(4))) float f32x4;

__device__ __forceinline__ void splitf(float v, f16* h, f16* l) {
    f16 hv = (f16)v;
    *h = hv;
    *l = (f16)(v - (float)hv);
}

// ---------------- weight conversion (transposed to [N][K], split hi/lo) ----
__global__ __launch_bounds__(256)
void conv_w1_kernel(const float* __restrict__ W1,
                    f16* __restrict__ Wh, f16* __restrict__ Wl) {
    int idx = blockIdx.x * 256 + threadIdx.x;
    if (idx >= NL * HDIM * K1) return;
    int l = idx / (HDIM * K1);
    int rem = idx - l * HDIM * K1;
    int n = rem / K1;
    int k = rem - n * K1;
    int row = (k < 128) ? (8 + k) : ((k < 136) ? (k - 128) : -1);
    float v = (row >= 0) ? W1[((size_t)l * 136 + row) * HDIM + n] : 0.f;
    f16 hv, lv; splitf(v, &hv, &lv);
    Wh[idx] = hv; Wl[idx] = lv;
}

__global__ __launch_bounds__(256)
void conv_w2_kernel(const float* __restrict__ W2,
                    f16* __restrict__ Wh, f16* __restrict__ Wl) {
    int idx = blockIdx.x * 256 + threadIdx.x;
    if (idx >= NL * HDIM * HDIM) return;
    int l = idx / (HDIM * HDIM);
    int rem = idx - l * HDIM * HDIM;
    int n = rem >> 8;
    int k = rem & 255;
    f16 hv, lv; splitf(W2[((size_t)l * HDIM + k) * HDIM + n], &hv, &lv);
    Wh[idx] = hv; Wl[idx] = lv;
}

__global__ __launch_bounds__(256)
void conv_w3_kernel(const float* __restrict__ W3,
                    f16* __restrict__ Wh, f16* __restrict__ Wl) {
    int idx = blockIdx.x * 256 + threadIdx.x;
    if (idx >= NL * N3P * HDIM) return;
    int l = idx / (N3P * HDIM);
    int rem = idx - l * N3P * HDIM;
    int n = rem >> 8;
    int k = rem & 255;
    float v = (n < N3) ? W3[((size_t)l * HDIM + k) * N3 + n] : 0.f;
    f16 hv, lv; splitf(v, &hv, &lv);
    Wh[idx] = hv; Wl[idx] = lv;
}

__global__ __launch_bounds__(256)
void conv_ctx_kernel(const float* __restrict__ ctx,
                     f16* __restrict__ ch, f16* __restrict__ cl) {
    size_t idx = ((size_t)blockIdx.x * 256 + threadIdx.x) * 4;
    if (idx >= (size_t)BATCH * CDIM) return;
    float4 v = *(const float4*)&ctx[idx];
    f16 h, l;
    splitf(v.x, &h, &l); ch[idx + 0] = h; cl[idx + 0] = l;
    splitf(v.y, &h, &l); ch[idx + 1] = h; cl[idx + 1] = l;
    splitf(v.z, &h, &l); ch[idx + 2] = h; cl[idx + 2] = l;
    splitf(v.w, &h, &l); ch[idx + 3] = h; cl[idx + 3] = l;
}

__device__ __forceinline__ float softplusf(float v) {
    return fmaxf(v, 0.f) + log1pf(expf(-fabsf(v)));
}

// ---------------- fused flow kernel ----------------
// 64 rows per WG, 256 threads (4 waves), 2 WG/CU. All 8 layers in one dispatch.
// sH: two 32KB f16 planes (hi/lo), XOR-swizzled [row][k] (row<64, k<256).
// Overlaid by sP (fp32 p buffer) between barriers.
__global__ __launch_bounds__(256, 2)
void flow_kernel(const float* __restrict__ in,
                 const f16* __restrict__ ctxh, const f16* __restrict__ ctxl,
                 const f16* __restrict__ W1h, const f16* __restrict__ W1l,
                 const f16* __restrict__ W2h, const f16* __restrict__ W2l,
                 const f16* __restrict__ W3h, const f16* __restrict__ W3l,
                 const float* __restrict__ b1, const float* __restrict__ b2,
                 const float* __restrict__ b3, const int* __restrict__ perms,
                 float* __restrict__ out) {
    __shared__ f16 sH[2 * 64 * 256];            // 64KB
    __shared__ float sX[2][64][17];
    __shared__ float sY[64][9];
    __shared__ float sLdp[4][64];
    __shared__ float sLdet[64];
    __shared__ int   sPerm[(NL - 1) * FDIM];

    const int tid = threadIdx.x;
    const int lane = tid & 63;
    const int w = tid >> 6;
    const int wr = w >> 1, wc = w & 1;
    const int lr = lane & 15, lh = lane >> 4;
    const int rbase = blockIdx.x * 64;
    float* sP = (float*)sH;                      // 64 x PSTR fp32 overlay

    // swizzled LDS helpers: byte = (row*512 + k*2) ^ ((row&7)<<4)
    auto lds_rd8 = [&](int plane, int row, int k) -> f16x8 {
        int byte = ((row << 9) + (k << 1)) ^ ((row & 7) << 4);
        return *(const f16x8*)((const char*)sH + plane * 32768 + byte);
    };
    auto lds_wr8 = [&](int plane, int row, int k, f16x8 v) {
        int byte = ((row << 9) + (k << 1)) ^ ((row & 7) << 4);
        *(f16x8*)((char*)sH + plane * 32768 + byte) = v;
    };
    auto lds_wr1 = [&](int plane, int row, int k, f16 v) {
        int byte = ((row << 9) + (k << 1)) ^ ((row & 7) << 4);
        *(f16*)((char*)sH + plane * 32768 + byte) = v;
    };

    // ---- init: x block, ldet, perms ----
    {
        int r = tid >> 2, c4 = (tid & 3) * 4;
        float4 v = *(const float4*)&in[(size_t)(rbase + r) * FDIM + c4];
        sX[0][r][c4 + 0] = fminf(fmaxf(v.x, -1.f), 1.f);
        sX[0][r][c4 + 1] = fminf(fmaxf(v.y, -1.f), 1.f);
        sX[0][r][c4 + 2] = fminf(fmaxf(v.z, -1.f), 1.f);
        sX[0][r][c4 + 3] = fminf(fmaxf(v.w, -1.f), 1.f);
    }
    if (tid < 64) sLdet[tid] = 0.f;
    if (tid < (NL - 1) * FDIM) sPerm[tid] = perms[tid];

    const int srow = tid >> 2, sc0 = (tid & 3) * 4;   // ctx staging: 4 chunks
    const f16* gph = ctxh + (((size_t)(rbase + srow)) << 7) + sc0 * 8;
    const f16* gpl = ctxl + (((size_t)(rbase + srow)) << 7) + sc0 * 8;

    int cur = 0;
    for (int l = 0; l < NL; ++l) {
        // ---- (A) issue ctx plane loads (global, L2/L3-hot) before the barrier
        f16x8 cbh[4], cbl[4];
        #pragma unroll
        for (int s = 0; s < 4; ++s) {
            cbh[s] = ((const f16x8*)gph)[s];
            cbl[s] = ((const f16x8*)gpl)[s];
        }
        __syncthreads();
        // ---- (B) stage A1: ctx chunks (k 0..127) ----
        #pragma unroll
        for (int s = 0; s < 4; ++s) {
            lds_wr8(0, srow, (sc0 + s) * 8, cbh[s]);
            lds_wr8(1, srow, (sc0 + s) * 8, cbl[s]);
        }
        // ---- xi (k 128..135) + zeros (136..159) ----
        if (tid < 64) {
            int r = tid, off = 1 - (l & 1);
            f16x8 h8, l8, z;
            #pragma unroll
            for (int k = 0; k < 8; ++k) {
                float v = sX[cur][r][2 * k + off];
                f16 hv, lv; splitf(v, &hv, &lv);
                h8[k] = hv; l8[k] = lv; z[k] = (f16)0.f;
            }
            lds_wr8(0, r, 128, h8); lds_wr8(1, r, 128, l8);
            lds_wr8(0, r, 136, z);  lds_wr8(1, r, 136, z);
            lds_wr8(0, r, 144, z);  lds_wr8(1, r, 144, z);
            lds_wr8(0, r, 152, z);  lds_wr8(1, r, 152, z);
        }
        __syncthreads();

        f32x4 acc[4][4];
        // ================= GEMM1: 256 cols, K=160 =================
        #pragma unroll
        for (int i = 0; i < 4; ++i)
            #pragma unroll
            for (int j = 0; j < 4; ++j) acc[i][j] = (f32x4){0.f, 0.f, 0.f, 0.f};
        for (int kt = 0; kt < 5; ++kt) {
            int k0 = kt * 32 + lh * 8;
            f16x8 ah[4], al[4];
            #pragma unroll
            for (int i = 0; i < 4; ++i) {
                ah[i] = lds_rd8(0, i * 16 + lr, k0);
                al[i] = lds_rd8(1, i * 16 + lr, k0);
            }
            #pragma unroll
            for (int j = 0; j < 4; ++j) {
                size_t o = (size_t)(l * HDIM + wc * 128 + j * 16 + lr + (j >= 2 ? 32 : 0)) * K1 + k0;
                // cols: wc*128 + {0..15,16..31,48..63,64..79}? keep simple contiguous:
                o = (size_t)(l * HDIM + wc * 128 + wr * 64 + ((j & 1) * 16) + ((j >> 1) * 32) + lr) * K1 + k0;
                f16x8 bh = *(const f16x8*)(W1h + o);
                f16x8 bl = *(const f16x8*)(W1l + o);
                __builtin_amdgcn_s_setprio(1);
                #pragma unroll
                for (int i = 0; i < 4; ++i) {
                    acc[i][j] = __builtin_amdgcn_mfma_f32_16x16x32_f16(ah[i], bh, acc[i][j], 0, 0, 0);
                    acc[i][j] = __builtin_amdgcn_mfma_f32_16x16x32_f16(ah[i], bl, acc[i][j], 0, 0, 0);
                    acc[i][j] = __builtin_amdgcn_mfma_f32_16x16x32_f16(al[i], bh, acc[i][j], 0, 0, 0);
                }
                __builtin_amdgcn_s_setprio(0);
            }
        }
        __syncthreads();
        // h1 = relu(acc + b1) -> split into sH
        #pragma unroll
        for (int j = 0; j < 4; ++j) {
            int col = wc * 128 + wr * 64 + ((j & 1) * 16) + ((j >> 1) * 32) + lr;
            float bv = b1[l * HDIM + col];
            #pragma unroll
            for (int i = 0; i < 4; ++i)
                #pragma unroll
                for (int q = 0; q < 4; ++q) {
                    float v = fmaxf(acc[i][j][q] + bv, 0.f);
                    f16 hv, lv; splitf(v, &hv, &lv);
                    int row = i * 16 + lh * 4 + q;
                    lds_wr1(0, row, col, hv);
                    lds_wr1(1, row, col, lv);
                }
        }
        __syncthreads();

        // ================= GEMM2: 256 cols, K=256 =================
        #pragma unroll
        for (int i = 0; i < 4; ++i)
            #pragma unroll
            for (int j = 0; j < 4; ++j) acc[i][j] = (f32x4){0.f, 0.f, 0.f, 0.f};
        for (int kt = 0; kt < 8; ++kt) {
            int k0 = kt * 32 + lh * 8;
            f16x8 ah[4], al[4];
            #pragma unroll
            for (int i = 0; i < 4; ++i) {
                ah[i] = lds_rd8(0, i * 16 + lr, k0);
                al[i] = lds_rd8(1, i * 16 + lr, k0);
            }
            #pragma unroll
            for (int j = 0; j < 4; ++j) {
                size_t o = (size_t)(l * HDIM + wc * 128 + wr * 64 + ((j & 1) * 16) + ((j >> 1) * 32) + lr) * HDIM + k0;
                f16x8 bh = *(const f16x8*)(W2h + o);
                f16x8 bl = *(const f16x8*)(W2l + o);
                __builtin_amdgcn_s_setprio(1);
                #pragma unroll
                for (int i = 0; i < 4; ++i) {
                    acc[i][j] = __builtin_amdgcn_mfma_f32_16x16x32_f16(ah[i], bh, acc[i][j], 0, 0, 0);
                    acc[i][j] = __builtin_amdgcn_mfma_f32_16x16x32_f16(ah[i], bl, acc[i][j], 0, 0, 0);
                    acc[i][j] = __builtin_amdgcn_mfma_f32_16x16x32_f16(al[i], bh, acc[i][j], 0, 0, 0);
                }
                __builtin_amdgcn_s_setprio(0);
            }
        }
        __syncthreads();
        // h2 = relu(acc + b2) -> split into sH
        #pragma unroll
        for (int j = 0; j < 4; ++j) {
            int col = wc * 128 + wr * 64 + ((j & 1) * 16) + ((j >> 1) * 32) + lr;
            float bv = b2[l * HDIM + col];
            #pragma unroll
            for (int i = 0; i < 4; ++i)
                #pragma unroll
                for (int q = 0; q < 4; ++q) {
                    float v = fmaxf(acc[i][j][q] + bv, 0.f);
                    f16 hv, lv; splitf(v, &hv, &lv);
                    int row = i * 16 + lh * 4 + q;
                    lds_wr1(0, row, col, hv);
                    lds_wr1(1, row, col, lv);
                }
        }
        __syncthreads();

        // ================= GEMM3: 192 cols (48/wave), K=256 =================
        f32x4 acc3[4][3];
        #pragma unroll
        for (int i = 0; i < 4; ++i)
            #pragma unroll
            for (int j = 0; j < 3; ++j) acc3[i][j] = (f32x4){0.f, 0.f, 0.f, 0.f};
        for (int kt = 0; kt < 8; ++kt) {
            int k0 = kt * 32 + lh * 8;
            f16x8 ah[4], al[4];
            #pragma unroll
            for (int i = 0; i < 4; ++i) {
                ah[i] = lds_rd8(0, i * 16 + lr, k0);
                al[i] = lds_rd8(1, i * 16 + lr, k0);
            }
            #pragma unroll
            for (int j = 0; j < 3; ++j) {
                size_t o = (size_t)(l * N3P + w * 48 + j * 16 + lr) * HDIM + k0;
                f16x8 bh = *(const f16x8*)(W3h + o);
                f16x8 bl = *(const f16x8*)(W3l + o);
                __builtin_amdgcn_s_setprio(1);
                #pragma unroll
                for (int i = 0; i < 4; ++i) {
                    acc3[i][j] = __builtin_amdgcn_mfma_f32_16x16x32_f16(ah[i], bh, acc3[i][j], 0, 0, 0);
                    acc3[i][j] = __builtin_amdgcn_mfma_f32_16x16x32_f16(ah[i], bl, acc3[i][j], 0, 0, 0);
                    acc3[i][j] = __builtin_amdgcn_mfma_f32_16x16x32_f16(al[i], bh, acc3[i][j], 0, 0, 0);
                }
                __builtin_amdgcn_s_setprio(0);
            }
        }
        __syncthreads();
        // p = acc3 + b3 -> sP (fp32, stride PSTR)
        #pragma unroll
        for (int j = 0; j < 3; ++j) {
            int col = w * 48 + j * 16 + lr;
            float bv = (col < N3) ? b3[l * N3 + col] : 0.f;
            #pragma unroll
            for (int i = 0; i < 4; ++i)
                #pragma unroll
                for (int q = 0; q < 4; ++q) {
                    int row = i * 16 + lh * 4 + q;
                    sP[row * PSTR + col] = acc3[i][j][q] + bv;
                }
        }
        __syncthreads();

        // ===== spline (register-light): wave w handles t = 2w, 2w+1 =====
        {
            int r = tid & 63, t2 = tid >> 6;
            float ldsum = 0.f;
            #pragma unroll
            for (int dt = 0; dt < 2; ++dt) {
                int t = t2 * 2 + dt;
                float xin = sX[cur][r][2 * t + (l & 1)];
                const float* pp = &sP[r * PSTR + t * PD];
                bool inside = (xin >= -TBV) && (xin <= TBV);
                float xs = fminf(fmaxf(xin, -TBV), TBV);

                // ---- widths: single pass, bin select ----
                float e0, e1, e2, e3, e4, e5, e6, e7;
                {
                    float a0 = pp[0], a1 = pp[1], a2 = pp[2], a3 = pp[3];
                    float a4 = pp[4], a5 = pp[5], a6 = pp[6], a7 = pp[7];
                    float m = fmaxf(fmaxf(fmaxf(a0, a1), fmaxf(a2, a3)),
                                    fmaxf(fmaxf(a4, a5), fmaxf(a6, a7)));
                    e0 = expf(a0 - m); e1 = expf(a1 - m); e2 = expf(a2 - m); e3 = expf(a3 - m);
                    e4 = expf(a4 - m); e5 = expf(a5 - m); e6 = expf(a6 - m); e7 = expf(a7 - m);
                }
                float swv = ((e0 + e1) + (e2 + e3)) + ((e4 + e5) + (e6 + e7));
                float cwc = (1.f - 0.001f * KBINS) / swv;
                float x0 = -TBV, x1 = TBV;
                int idx = 0;
                bool done = false;
                {
                    float cs = 0.f;
                    float ee[7] = {e0, e1, e2, e3, e4, e5, e6};
                    #pragma unroll
                    for (int k = 0; k < 7; ++k) {
                        cs += 0.001f + cwc * ee[k];
                        float nxt = 2.f * TBV * cs - TBV;
                        bool ge = (xs >= nxt);
                        x0 = ge ? nxt : x0;
                        idx += ge ? 1 : 0;
                        x1 = (!ge && !done) ? nxt : x1;
                        done = done || !ge;
                    }
                }
                // ---- heights: single pass, select at idx ----
                float y0 = -TBV, y1 = TBV;
                {
                    float a0 = pp[8], a1 = pp[9], a2 = pp[10], a3 = pp[11];
                    float a4 = pp[12], a5 = pp[13], a6 = pp[14], a7 = pp[15];
                    float m = fmaxf(fmaxf(fmaxf(a0, a1), fmaxf(a2, a3)),
                                    fmaxf(fmaxf(a4, a5), fmaxf(a6, a7)));
                    float f0 = expf(a0 - m), f1 = expf(a1 - m), f2 = expf(a2 - m), f3 = expf(a3 - m);
                    float f4 = expf(a4 - m), f5 = expf(a5 - m), f6 = expf(a6 - m), f7 = expf(a7 - m);
                    float shv = ((f0 + f1) + (f2 + f3)) + ((f4 + f5) + (f6 + f7));
                    float chc = (1.f - 0.001f * KBINS) / shv;
                    float cs = 0.f;
                    float ff[7] = {f0, f1, f2, f3, f4, f5, f6};
                    #pragma unroll
                    for (int k = 0; k < 7; ++k) {
                        cs += 0.001f + chc * ff[k];
                        float nxt = 2.f * TBV * cs - TBV;
                        y0 = (k < idx) ? nxt : y0;
                        y1 = (k == idx) ? nxt : y1;
                    }
                }
                // ---- derivatives: only the two needed, via dynamic LDS read ----
                float udm = pp[16 + (idx > 0 ? idx - 1 : 0)];
                float udp = pp[16 + (idx < 7 ? idx : 6)];
                float d0 = (idx > 0) ? 0.001f + softplusf(udm) : 1.f;
                float d1 = (idx < 7) ? 0.001f + softplusf(udp) : 1.f;

                float bw = x1 - x0, bh2 = y1 - y0;
                float delta = bh2 / bw;
                float th = (xs - x0) / bw;
                float th1m = th * (1.f - th);
                float num = bh2 * (delta * th * th + d0 * th1m);
                float den = delta + (d0 + d1 - 2.f * delta) * th1m;
                float y = y0 + num / den;
                float omth = 1.f - th;
                float dnum = delta * delta * (d1 * th * th + 2.f * delta * th1m + d0 * omth * omth);
                float ldv = logf(dnum) - 2.f * logf(den);
                sY[r][t] = inside ? y : xin;
                ldsum += inside ? ldv : 0.f;
            }
            sLdp[t2][tid & 63] = ldsum;
        }
        __syncthreads();

        // ================= rebuild x (+perm) and ldet, 256 threads =================
        {
            int r = tid >> 2, f0 = (tid & 3) * 4;
            if (l < NL - 1) {
                #pragma unroll
                for (int ff = 0; ff < 4; ++ff) {
                    int f = f0 + ff;
                    int g = sPerm[l * FDIM + f];
                    float v = ((g & 1) == (l & 1)) ? sY[r][g >> 1] : sX[cur][r][g];
                    sX[cur ^ 1][r][f] = v;
                }
                if (f0 == 0)
                    sLdet[r] += sLdp[0][r] + sLdp[1][r] + sLdp[2][r] + sLdp[3][r];
            } else {
                float ov[4];
                #pragma unroll
                for (int ff = 0; ff < 4; ++ff) {
                    int f = f0 + ff;
                    float v = ((f & 1) == (l & 1)) ? sY[r][f >> 1] : sX[cur][r][f];
                    ov[ff] = fminf(fmaxf(v, -1.f), 1.f);
                }
                float4 o = {ov[0], ov[1], ov[2], ov[3]};
                *(float4*)&out[(size_t)(rbase + r) * FDIM + f0] = o;
                if (f0 == 0)
                    out[(size_t)BATCH * FDIM + rbase + r] =
                        sLdet[r] + sLdp[0][r] + sLdp[1][r] + sLdp[2][r] + sLdp[3][r];
            }
        }
        cur ^= 1;
    }
}

extern "C" void kernel_launch(void* const* d_in, const int* in_sizes, int n_in,
                              void* d_out, int out_size, void* d_ws, size_t ws_size,
                              hipStream_t stream) {
    (void)in_sizes; (void)n_in; (void)out_size; (void)ws_size;
    const float* inputs  = (const float*)d_in[0];
    const float* context = (const float*)d_in[1];
    const float* W1 = (const float*)d_in[2];
    const float* b1 = (const float*)d_in[3];
    const float* W2 = (const float*)d_in[4];
    const float* b2 = (const float*)d_in[5];
    const float* W3 = (const float*)d_in[6];
    const float* b3 = (const float*)d_in[7];
    const int*   perms = (const int*)d_in[8];
    float* out = (float*)d_out;

    f16* W1h = (f16*)d_ws;
    f16* W1l = W1h + (size_t)NL * HDIM * K1;
    f16* W2h = W1l + (size_t)NL * HDIM * K1;
    f16* W2l = W2h + (size_t)NL * HDIM * HDIM;
    f16* W3h = W2l + (size_t)NL * HDIM * HDIM;
    f16* W3l = W3h + (size_t)NL * N3P * HDIM;
    f16* ctxh = W3l + (size_t)NL * N3P * HDIM;
    f16* ctxl = ctxh + (size_t)BATCH * CDIM;

    int n1 = NL * HDIM * K1;
    conv_w1_kernel<<<(n1 + 255) / 256, 256, 0, stream>>>(W1, W1h, W1l);
    int n2 = NL * HDIM * HDIM;
    conv_w2_kernel<<<(n2 + 255) / 256, 256, 0, stream>>>(W2, W2h, W2l);
    int n3 = NL * N3P * HDIM;
    conv_w3_kernel<<<(n3 + 255) / 256, 256, 0, stream>>>(W3, W3h, W3l);
    int nc = BATCH * CDIM / 4;
    conv_ctx_kernel<<<(nc + 255) / 256, 256, 0, stream>>>(context, ctxh, ctxl);

    flow_kernel<<<BATCH / 64, 256, 0, stream>>>(
        inputs, ctxh, ctxl, W1h, W1l, W2h, W2l, W3h, W3l,
        b1, b2, b3, perms, out);
}